// Round 2
// baseline (109.971 us; speedup 1.0000x reference)
//
#include <hip/hip_runtime.h>
#include <hip/hip_bf16.h>

// N=8192 rows, D=64. chord mask has exactly 2 nonzeros/row: (i,i) and (i,(i+1)%N).
// So W@V collapses to V_new[i] = a_i*V[i] + b_i*V[(i+1)%N] where a_i, b_i are the two
// surviving entries of relu(T @ fL_w^T + fL_b). The 8192x8192 score matrix is never formed.
// ALL reference dtypes are float32 -> inputs/outputs are float* (R1 inf failure was a
// bf16 misread of fp32 data).

#define NROWS 8192
#define DIN 64

// V0 = relu(relu(X @ g_w0^T + g_b0) @ g_w1^T + g_b1)
// One wave per row; lane j owns output column j. Weights in LDS padded [64][65]:
// read addr j*65+k -> bank (j+k)%32 -> 2-way alias across 64 lanes (free per m136).
__global__ __launch_bounds__(256) void gstack_kernel(
    const float* __restrict__ X, const float* __restrict__ g_w,
    const float* __restrict__ g_b, float* __restrict__ V)
{
    __shared__ float w0[64][65];
    __shared__ float w1[64][65];
    __shared__ float b0[64];
    __shared__ float b1[64];
    const int tid = threadIdx.x;
#pragma unroll
    for (int e = 0; e < 16; ++e) {
        int idx = e * 256 + tid;       // coalesced global read, conflict-free LDS write
        int j = idx >> 6, k = idx & 63;
        w0[j][k] = g_w[idx];
        w1[j][k] = g_w[4096 + idx];
    }
    if (tid < 64) { b0[tid] = g_b[tid]; b1[tid] = g_b[64 + tid]; }
    __syncthreads();

    const int row  = blockIdx.x * 4 + (tid >> 6);
    const int lane = tid & 63;

    float x = X[row * 64 + lane];

    float acc = b0[lane];
#pragma unroll
    for (int k = 0; k < 64; ++k)
        acc = fmaf(__shfl(x, k, 64), w0[lane][k], acc);
    float v1 = fmaxf(acc, 0.0f);

    acc = b1[lane];
#pragma unroll
    for (int k = 0; k < 64; ++k)
        acc = fmaf(__shfl(v1, k, 64), w1[lane][k], acc);

    V[row * 64 + lane] = fmaxf(acc, 0.0f);
}

// One chord layer:
//   T_i = relu(X[i] @ f0_w^T + f0_b)                      (row x 64x64)
//   a_i = relu(dot(T_i, fL_w[i])   + fL_b[i])
//   b_i = relu(dot(T_i, fL_w[i+1]) + fL_b[i+1])           (wrapped)
//   Vout[i] = a_i * Vin[i] + b_i * Vin[i+1]
__global__ __launch_bounds__(256) void layer_kernel(
    const float* __restrict__ X, const float* __restrict__ f0w,
    const float* __restrict__ f0b, const float* __restrict__ fLw,
    const float* __restrict__ fLb, const float* __restrict__ Vin,
    float* __restrict__ Vout)
{
    __shared__ float w[64][65];
    __shared__ float b[64];
    const int tid = threadIdx.x;
#pragma unroll
    for (int e = 0; e < 16; ++e) {
        int idx = e * 256 + tid;
        int j = idx >> 6, k = idx & 63;
        w[j][k] = f0w[idx];
    }
    if (tid < 64) b[tid] = f0b[tid];
    __syncthreads();

    const int row  = blockIdx.x * 4 + (tid >> 6);
    const int lane = tid & 63;

    float x = X[row * 64 + lane];
    float acc = b[lane];
#pragma unroll
    for (int k = 0; k < 64; ++k)
        acc = fmaf(__shfl(x, k, 64), w[lane][k], acc);
    float t = fmaxf(acc, 0.0f);

    const int rp1 = (row + 1) & (NROWS - 1);

    // two dot-64s against fL_w rows i and i+1 (coalesced fp32 reads)
    float pa = t * fLw[row * 64 + lane];
    float pb = t * fLw[rp1 * 64 + lane];
#pragma unroll
    for (int off = 32; off > 0; off >>= 1) {
        pa += __shfl_xor(pa, off, 64);
        pb += __shfl_xor(pb, off, 64);
    }
    float a  = fmaxf(pa + fLb[row], 0.0f);
    float bb = fmaxf(pb + fLb[rp1], 0.0f);

    Vout[row * 64 + lane] = a * Vin[row * 64 + lane] + bb * Vin[rp1 * 64 + lane];
}

extern "C" void kernel_launch(void* const* d_in, const int* in_sizes, int n_in,
                              void* d_out, int out_size, void* d_ws, size_t ws_size,
                              hipStream_t stream) {
    const float* X    = (const float*)d_in[0];  // [8192,64]
    const float* g_w  = (const float*)d_in[1];  // [2,64,64]
    const float* g_b  = (const float*)d_in[2];  // [2,64]
    const float* f0_w = (const float*)d_in[3];  // [2,64,64]
    const float* f0_b = (const float*)d_in[4];  // [2,64]
    const float* fL_w = (const float*)d_in[5];  // [2,8192,64]
    const float* fL_b = (const float*)d_in[6];  // [2,8192]
    float* out = (float*)d_out;                 // [8192,64] fp32

    float* Va = (float*)d_ws;                   // [8192*64] f32
    float* Vb = Va + NROWS * DIN;               // [8192*64] f32

    const dim3 grid(NROWS / 4), block(256);

    gstack_kernel<<<grid, block, 0, stream>>>(X, g_w, g_b, Va);
    layer_kernel<<<grid, block, 0, stream>>>(X, f0_w, f0_b,
                                             fL_w, fL_b, Va, Vb);
    layer_kernel<<<grid, block, 0, stream>>>(X, f0_w + 64 * 64, f0_b + 64,
                                             fL_w + NROWS * 64, fL_b + NROWS,
                                             Vb, out);
}

// Round 3
// 87.764 us; speedup vs baseline: 1.2530x; 1.2530x over previous
//
#include <hip/hip_runtime.h>

// Fully fused SMFNet. N=8192, D=64. chord mask = diag + wrapped superdiag, so
// W@V == V_new[i] = a_i*V[i] + b_i*V[(i+1)%N]. One block = 16 output rows;
// it computes V0 for 20 context rows, V1 for 19, out for 16 (neighbor chain).
// DS-pipe diet (R2 was DS-bound at 2 DS ops/fma):
//  - A-operand broadcast via v_readlane (VALU), not ds_bpermute
//  - W via lane-contiguous ds_read_b128 from k-chunked LDS: 1 DS op / 20 fma
//  - dot-64 reductions via DPP row_ror (VALU) + readlane, zero DS

#define NROWS 8192
#define BROWS 16   // output rows per block
#define RPW 5      // rows per wave (4 waves * 5 = 20 context rows)

__device__ __forceinline__ float rl(float v, int lane) {
  return __int_as_float(__builtin_amdgcn_readlane(__float_as_int(v), lane));
}

// full-wave (64 lane) sum; result uniform across lanes. DPP row_ror 1/2/4/8
// reduces within each 16-lane row (VALU pipe), readlane combines the 4 rows.
__device__ __forceinline__ float wave_sum(float x) {
  x += __int_as_float(__builtin_amdgcn_update_dpp(0, __float_as_int(x), 0x121, 0xF, 0xF, false));
  x += __int_as_float(__builtin_amdgcn_update_dpp(0, __float_as_int(x), 0x122, 0xF, 0xF, false));
  x += __int_as_float(__builtin_amdgcn_update_dpp(0, __float_as_int(x), 0x124, 0xF, 0xF, false));
  x += __int_as_float(__builtin_amdgcn_update_dpp(0, __float_as_int(x), 0x128, 0xF, 0xF, false));
  float a0 = rl(x, 0), a1 = rl(x, 16), a2 = rl(x, 32), a3 = rl(x, 48);
  return (a0 + a1) + (a2 + a3);
}

// stage 64x64 row-major W into k-chunked LDS: Wq[kb][j] = {W[j][4kb..4kb+3]}
__device__ __forceinline__ void stageW(float4 (*Wq)[65], const float* __restrict__ W, int tid) {
  const float4* ws = (const float4*)W;
#pragma unroll
  for (int p = 0; p < 4; ++p) {
    int idx = p * 256 + tid;              // coalesced global float4 read
    Wq[idx & 15][idx >> 4] = ws[idx];     // one-time LDS write
  }
}

// acc[r] = relu(sum_k src[r broadcast k]*W[lane][k] + bias); src lane=col regs
template <int R>
__device__ __forceinline__ void mm64(const float4 (*Wq)[65], int lane,
                                     const float* src, float bias, float* acc) {
#pragma unroll
  for (int r = 0; r < R; ++r) acc[r] = bias;
#pragma unroll 4
  for (int kb = 0; kb < 16; ++kb) {
    float4 w4 = Wq[kb][lane];             // ds_read_b128, lane-contiguous
#pragma unroll
    for (int r = 0; r < R; ++r) {
      acc[r] = fmaf(rl(src[r], 4 * kb + 0), w4.x, acc[r]);
      acc[r] = fmaf(rl(src[r], 4 * kb + 1), w4.y, acc[r]);
      acc[r] = fmaf(rl(src[r], 4 * kb + 2), w4.z, acc[r]);
      acc[r] = fmaf(rl(src[r], 4 * kb + 3), w4.w, acc[r]);
    }
  }
#pragma unroll
  for (int r = 0; r < R; ++r) acc[r] = fmaxf(acc[r], 0.0f);
}

__global__ __launch_bounds__(256, 2) void fused_smfnet(
    const float* __restrict__ X, const float* __restrict__ g_w,
    const float* __restrict__ g_b, const float* __restrict__ f0_w,
    const float* __restrict__ f0_b, const float* __restrict__ fL_w,
    const float* __restrict__ fL_b, float* __restrict__ out)
{
  __shared__ float4 Wq[16][65];     // 16.6 KB, reloaded per matmul
  __shared__ float V0s[20][65];     // neighbor access for chord combine
  __shared__ float V1s[19][65];

  const int tid  = threadIdx.x;
  const int lane = tid & 63;
  const int wv   = tid >> 6;                 // wave id 0..3
  const int r0   = blockIdx.x * BROWS;

  stageW(Wq, g_w, tid);                      // g0
  float hb  = g_b[lane];
  float vb  = g_b[64 + lane];

  float xr[RPW];                             // X rows, lane=col
  int grow[RPW];
#pragma unroll
  for (int r = 0; r < RPW; ++r) {
    int L = wv * RPW + r;
    grow[r] = (r0 + L) & (NROWS - 1);
    xr[r] = X[grow[r] * 64 + lane];
  }
  __syncthreads();

  float h[RPW];
  mm64<RPW>(Wq, lane, xr, hb, h);            // H = relu(X @ g0^T + b0)

  __syncthreads();                           // everyone done with g0
  stageW(Wq, g_w + 4096, tid);               // g1
  __syncthreads();

  float v0[RPW];
  mm64<RPW>(Wq, lane, h, vb, v0);            // V0 = relu(H @ g1^T + b1)
#pragma unroll
  for (int r = 0; r < RPW; ++r) V0s[wv * RPW + r][lane] = v0[r];

  __syncthreads();                           // g1 done, V0s visible
  stageW(Wq, f0_w, tid);                     // f0 layer 0
  __syncthreads();

  float tb0 = f0_b[lane];
  float t[RPW];
  mm64<RPW>(Wq, lane, xr, tb0, t);           // T0 = relu(X @ f00^T + b)

  float v1[RPW];
#pragma unroll
  for (int r = 0; r < RPW; ++r) {
    int L = wv * RPW + r;
    if (L <= 18) {                           // wave-uniform predicate
      int g   = grow[r];
      int gp1 = (g + 1) & (NROWS - 1);
      float pa = wave_sum(t[r] * fL_w[g * 64 + lane]);
      float pb = wave_sum(t[r] * fL_w[gp1 * 64 + lane]);
      float a  = fmaxf(pa + fL_b[g], 0.0f);
      float b  = fmaxf(pb + fL_b[gp1], 0.0f);
      v1[r] = a * v0[r] + b * V0s[L + 1][lane];
      V1s[L][lane] = v1[r];
    }
  }

  __syncthreads();                           // f00 done, V1s visible
  stageW(Wq, f0_w + 4096, tid);              // f0 layer 1
  __syncthreads();

  float tb1 = f0_b[64 + lane];
  mm64<RPW>(Wq, lane, xr, tb1, t);           // T1 = relu(X @ f01^T + b)

  const float* fw1 = fL_w + NROWS * 64;
  const float* fb1 = fL_b + NROWS;
#pragma unroll
  for (int r = 0; r < RPW; ++r) {
    int L = wv * RPW + r;
    if (L <= 15) {
      int g   = grow[r];
      int gp1 = (g + 1) & (NROWS - 1);
      float pa = wave_sum(t[r] * fw1[g * 64 + lane]);
      float pb = wave_sum(t[r] * fw1[gp1 * 64 + lane]);
      float a  = fmaxf(pa + fb1[g], 0.0f);
      float b  = fmaxf(pb + fb1[gp1], 0.0f);
      out[g * 64 + lane] = a * v1[r] + b * V1s[L + 1][lane];
    }
  }
}

extern "C" void kernel_launch(void* const* d_in, const int* in_sizes, int n_in,
                              void* d_out, int out_size, void* d_ws, size_t ws_size,
                              hipStream_t stream) {
  const float* X    = (const float*)d_in[0];  // [8192,64]
  const float* g_w  = (const float*)d_in[1];  // [2,64,64]
  const float* g_b  = (const float*)d_in[2];  // [2,64]
  const float* f0_w = (const float*)d_in[3];  // [2,64,64]
  const float* f0_b = (const float*)d_in[4];  // [2,64]
  const float* fL_w = (const float*)d_in[5];  // [2,8192,64]
  const float* fL_b = (const float*)d_in[6];  // [2,8192]
  float* out = (float*)d_out;                 // [8192,64] fp32

  fused_smfnet<<<dim3(NROWS / BROWS), dim3(256), 0, stream>>>(
      X, g_w, g_b, f0_w, f0_b, fL_w, fL_b, out);
}